// Round 1
// baseline (925.384 us; speedup 1.0000x reference)
//
#include <hip/hip_runtime.h>

// ---------------- problem constants ----------------
#define NUM_ENT   100000
#define NTIMES    10000
#define DD        512
#define DB        768
#define NREL      200
#define NBAS      4
#define NN        30000
#define NEDGE     200000
#define BATCH     128
#define PENT      64
#define PTIME     32
#define TUNIQ     2000
#define V_TOT     110000      // NUM_ENT + NTIMES
#define V_PAD     110208      // 861*128
#define VT16      6888        // V_PAD/16
#define M_PAD     30080       // 235*128
#define KT_L      80          // 2560/32  (layer GEMM k-tiles)
#define KT_E      16          // 512/32

typedef __attribute__((ext_vector_type(8))) short s8v;   // 8 x bf16 bits
typedef __attribute__((ext_vector_type(4))) float f4v;   // mfma accumulator

__device__ __forceinline__ unsigned short f2bf(float x){
  unsigned int u = __builtin_bit_cast(unsigned int, x);
  u += 0x7fffu + ((u >> 16) & 1u);
  return (unsigned short)(u >> 16);
}
__device__ __forceinline__ float bf2f(unsigned short h){
  unsigned int u = ((unsigned int)h) << 16;
  return __builtin_bit_cast(float, u);
}

// Fragment-major ("MFMA native") layouts:
//  A-layout: Ap[(row/16)*Kt + (k/32)] is a 1KB block; element (lane,j):
//            row = 16*rt + (lane&15), k = 32*kt + (lane>>4)*8 + j
//  B-layout: Bp[(k/32)*Nt16 + (col/16)] 1KB block; element (lane,j):
//            col = 16*ct + (lane&15), k = 32*kt + (lane>>4)*8 + j

// ---------------- emb -> bf16 B-layout + invnorm ----------------
__global__ __launch_bounds__(256) void k_conv_emb(const float* __restrict__ emb,
    unsigned short* __restrict__ Bp, float* __restrict__ invn){
  int vt = blockIdx.x;                       // 0..VT16-1
  int wid = threadIdx.x >> 6, lane = threadIdx.x & 63;
  int vrow = vt * 16 + (lane & 15);
  float ss = 0.f;
  __shared__ float ssw[4][16];
  for (int i = 0; i < 4; ++i){
    int kt = wid + i * 4;
    int k0 = kt * 32 + (lane >> 4) * 8;
    s8v o;
    if (vrow < V_TOT){
      const float* p = emb + (size_t)vrow * DD + k0;
      #pragma unroll
      for (int j = 0; j < 8; ++j){ float x = p[j]; ss += x * x; o[j] = (short)f2bf(x); }
    } else {
      #pragma unroll
      for (int j = 0; j < 8; ++j) o[j] = 0;
    }
    *reinterpret_cast<s8v*>(Bp + ((size_t)(kt * VT16 + vt) << 9) + lane * 8) = o;
  }
  ss += __shfl_xor(ss, 16);
  ss += __shfl_xor(ss, 32);
  if ((lane >> 4) == 0) ssw[wid][lane] = ss;
  __syncthreads();
  if (threadIdx.x < 16){
    float s = ssw[0][threadIdx.x] + ssw[1][threadIdx.x] + ssw[2][threadIdx.x] + ssw[3][threadIdx.x];
    int v = vt * 16 + threadIdx.x;
    invn[v] = (v < V_TOT) ? (1.0f / fmaxf(sqrtf(s), 1e-8f)) : 0.0f;
  }
}

// ---------------- small dense: q_lin, q_attn, p_ent ----------------
__global__ __launch_bounds__(256) void k_small(const float* __restrict__ ques,
    const float* __restrict__ Wl, const float* __restrict__ bl,
    const float* __restrict__ Wa, const float* __restrict__ ba,
    const float* __restrict__ Wp, const float* __restrict__ bp,
    float* __restrict__ qlin, float* __restrict__ qattn, float* __restrict__ pent){
  int b = blockIdx.x;
  __shared__ float sq[DB];
  for (int i = threadIdx.x; i < DB; i += 256) sq[i] = ques[(size_t)b * DB + i];
  __syncthreads();
  for (int i = 0; i < 4; ++i){
    int n = threadIdx.x + 256 * i;
    const float* W; const float* bb; float* dst; int col;
    if (n < 512){ W = Wl; bb = bl; dst = qlin; col = n; }
    else        { W = Wa; bb = ba; dst = qattn; col = n - 512; }
    float acc = 0.f;
    for (int k = 0; k < DB; ++k) acc = fmaf(sq[k], W[(size_t)k * 512 + col], acc);
    dst[(size_t)b * 512 + col] = acc + bb[col];
  }
  if (threadIdx.x < 64){
    float a = 0.f;
    for (int k = threadIdx.x; k < DB; k += 64) a = fmaf(sq[k], Wp[k], a);
    a += __shfl_xor(a, 32); a += __shfl_xor(a, 16); a += __shfl_xor(a, 8);
    a += __shfl_xor(a, 4);  a += __shfl_xor(a, 2);  a += __shfl_xor(a, 1);
    if (threadIdx.x == 0) pent[b] = 1.f / (1.f + expf(-(a + bp[0])));
  }
}

// ---------------- pack f32 [128][512] rows -> A-layout bf16 (Kt=16) ----------------
__global__ __launch_bounds__(256) void k_pack_qrows(const float* __restrict__ src,
    unsigned short* __restrict__ Ap){
  int w = (int)((blockIdx.x * 256 + threadIdx.x) >> 6);
  int lane = threadIdx.x & 63;
  if (w >= BATCH) return;
  const float* p = src + (size_t)w * 512 + lane * 8;
  s8v o;
  #pragma unroll
  for (int j = 0; j < 8; ++j) o[j] = (short)f2bf(p[j]);
  *reinterpret_cast<s8v*>(Ap + ((size_t)((w >> 4) * KT_E + (lane >> 2)) << 9)
                             + ((w & 15) + (lane & 3) * 16) * 8) = o;
}

// ---------------- pack basis||root (f32) -> B-layout bf16 (Kt=80, Nt=32) ----------------
__global__ __launch_bounds__(256) void k_pack_B(const float* __restrict__ basis,
    const float* __restrict__ root, unsigned short* __restrict__ Bp){
  int idx = blockIdx.x * 256 + threadIdx.x;        // chunk = (kt,ct,lane)
  if (idx >= KT_L * 32 * 64) return;
  int lane = idx & 63; int kt = idx >> 11;
  int k0 = kt * 32 + (lane >> 4) * 8;
  int col = ((idx >> 6) & 31) * 16 + (lane & 15);
  s8v o;
  #pragma unroll
  for (int j = 0; j < 8; ++j){
    int k = k0 + j;
    float v = (k < 2048) ? basis[(size_t)k * 512 + col] : root[(size_t)(k - 2048) * 512 + col];
    o[j] = (short)f2bf(v);
  }
  *reinterpret_cast<s8v*>(Bp + (size_t)idx * 8) = o;
}

// ---------------- generic 128x128 bf16 MFMA GEMM, fragment-major operands ----------------
// MODE 0: M2 f32 [128][10000]   MODE 1: h1 bf16 [NN][512] bias+relu
// MODE 2: h2 f32 [NN][512] bias MODE 3: score f32 [128][V_TOT] *invnorm*30
template<int MODE>
__global__ __launch_bounds__(256) void k_gemm(
    const unsigned short* __restrict__ A, const unsigned short* __restrict__ B,
    int Kt, int Bt_stride, int ct_off,
    const float* __restrict__ bias, const float* __restrict__ invn,
    float* __restrict__ outf, unsigned short* __restrict__ outh){
  __shared__ short sA[4096];
  __shared__ short sB[4096];
  int tid = threadIdx.x;
  int lane = tid & 63, wid = tid >> 6;
  int wr = wid >> 1, wc = wid & 1;
  int rt0 = blockIdx.x * 8;
  int ct0 = blockIdx.y * 8 + ct_off;
  const unsigned short* ga = A + ((size_t)(rt0 + (tid >> 5)) * (size_t)Kt) * 512 + (tid & 31) * 16;
  const unsigned short* gb = B + ((size_t)(ct0 + (tid >> 5))) * 512 + (tid & 31) * 16;
  size_t gb_step = (size_t)Bt_stride * 512;
  f4v acc[4][4] = {};
  for (int kt = 0; kt < Kt; ++kt){
    s8v a0 = *reinterpret_cast<const s8v*>(ga);
    s8v a1 = *reinterpret_cast<const s8v*>(ga + 8);
    s8v b0 = *reinterpret_cast<const s8v*>(gb);
    s8v b1 = *reinterpret_cast<const s8v*>(gb + 8);
    __syncthreads();
    *reinterpret_cast<s8v*>(&sA[tid * 16]) = a0;
    *reinterpret_cast<s8v*>(&sA[tid * 16 + 8]) = a1;
    *reinterpret_cast<s8v*>(&sB[tid * 16]) = b0;
    *reinterpret_cast<s8v*>(&sB[tid * 16 + 8]) = b1;
    __syncthreads();
    s8v af[4], bfr[4];
    #pragma unroll
    for (int m = 0; m < 4; ++m) af[m] = *reinterpret_cast<const s8v*>(&sA[(wr * 4 + m) * 512 + lane * 8]);
    #pragma unroll
    for (int n = 0; n < 4; ++n) bfr[n] = *reinterpret_cast<const s8v*>(&sB[(wc * 4 + n) * 512 + lane * 8]);
    #pragma unroll
    for (int m = 0; m < 4; ++m)
      #pragma unroll
      for (int n = 0; n < 4; ++n)
        acc[m][n] = __builtin_amdgcn_mfma_f32_16x16x32_bf16(af[m], bfr[n], acc[m][n], 0, 0, 0);
    ga += 512; gb += gb_step;
  }
  #pragma unroll
  for (int m = 0; m < 4; ++m)
    #pragma unroll
    for (int n = 0; n < 4; ++n){
      int row0 = rt0 * 16 + (wr * 4 + m) * 16 + ((lane >> 4) * 4);
      int col  = (blockIdx.y * 8 + (wc * 4 + n)) * 16 + (lane & 15);
      #pragma unroll
      for (int r = 0; r < 4; ++r){
        float c = acc[m][n][r];
        int rr = row0 + r;
        if constexpr (MODE == 0){
          if (col < NTIMES) outf[(size_t)rr * NTIMES + col] = c;
        } else if constexpr (MODE == 1){
          if (rr < NN){ float v = fmaxf(c + bias[col], 0.f); outh[(size_t)rr * 512 + col] = f2bf(v); }
        } else if constexpr (MODE == 2){
          if (rr < NN) outf[(size_t)rr * 512 + col] = c + bias[col];
        } else {
          if (col < V_TOT) outf[(size_t)rr * V_TOT + col] = c * invn[col] * 30.0f;
        }
      }
    }
}

// ---------------- per-edge gate weight ----------------
__global__ __launch_bounds__(256) void k_edge_w(const int* __restrict__ ebatch,
    const int* __restrict__ st, const int* __restrict__ et,
    const float* __restrict__ enorm, const float* __restrict__ M2,
    float* __restrict__ we){
  int e = blockIdx.x * 256 + threadIdx.x;
  if (e >= NEDGE) return;
  int b = ebatch[e];
  float s = 0.5f * (M2[(size_t)b * NTIMES + st[e]] + M2[(size_t)b * NTIMES + et[e]]);
  we[e] = (1.f / (1.f + expf(-s))) * enorm[e];
}

// ---------------- bucket edges by dst ----------------
__global__ __launch_bounds__(256) void k_count(const int* __restrict__ ei,
    int* __restrict__ cnt, int* __restrict__ lists){
  int e = blockIdx.x * 256 + threadIdx.x;
  if (e >= NEDGE) return;
  int dst = ei[NEDGE + e];
  int slot = atomicAdd(&cnt[dst], 1);
  if (slot < 64) lists[(size_t)dst * 64 + slot] = e;
}

// ---------------- gather x rows (bf16) + write A-tail ----------------
__global__ __launch_bounds__(256) void k_gather_x(const int* __restrict__ x_idx,
    const unsigned short* __restrict__ Bp, unsigned short* __restrict__ Ap,
    unsigned short* __restrict__ x_rm){
  int w = (int)((blockIdx.x * 256 + threadIdx.x) >> 6);
  int lane = threadIdx.x & 63;
  if (w >= NN) return;
  int v = x_idx[w];
  s8v x = *reinterpret_cast<const s8v*>(
      Bp + ((size_t)(lane >> 2) * VT16 + (v >> 4)) * 512 + ((v & 15) + (lane & 3) * 16) * 8);
  *reinterpret_cast<s8v*>(x_rm + (size_t)w * 512 + lane * 8) = x;
  *reinterpret_cast<s8v*>(Ap + ((size_t)(w >> 4) * KT_L + 64 + (lane >> 2)) * 512
                             + ((w & 15) + (lane & 3) * 16) * 8) = x;
}

// ---------------- pack h1 rows -> A-tail ----------------
__global__ __launch_bounds__(256) void k_pack_rows(const unsigned short* __restrict__ src_rm,
    unsigned short* __restrict__ Ap){
  int w = (int)((blockIdx.x * 256 + threadIdx.x) >> 6);
  int lane = threadIdx.x & 63;
  if (w >= NN) return;
  s8v x = *reinterpret_cast<const s8v*>(src_rm + (size_t)w * 512 + lane * 8);
  *reinterpret_cast<s8v*>(Ap + ((size_t)(w >> 4) * KT_L + 64 + (lane >> 2)) * 512
                             + ((w & 15) + (lane & 3) * 16) * 8) = x;
}

// ---------------- edge aggregation: z[n,b,:] += (w*att[t,b]) * x[src,:] ----------------
__global__ __launch_bounds__(256) void k_edge_agg(const unsigned short* __restrict__ xsrc,
    const int* __restrict__ ei, const int* __restrict__ etype,
    const float* __restrict__ we, const float* __restrict__ att,
    const int* __restrict__ cnt, const int* __restrict__ lists,
    unsigned short* __restrict__ Ap){
  __shared__ float satt[NREL * NBAS];
  __shared__ int sed[4][64];
  for (int i = threadIdx.x; i < NREL * NBAS; i += 256) satt[i] = att[i];
  int wid = threadIdx.x >> 6, lane = threadIdx.x & 63;
  int n = blockIdx.x * 4 + wid;                 // grid sized so n < NN always
  int deg = min(cnt[n], 64);
  // canonical (ascending edge-id) order for determinism
  int eid = (lane < deg) ? lists[(size_t)n * 64 + lane] : 0x7fffffff;
  int rank = 0;
  for (int j = 0; j < deg; ++j){
    int v = __shfl(eid, j);
    if (lane < deg && v < eid) rank++;
  }
  __syncthreads();              // satt ready; also orders sed writes below? (write after)
  if (lane < deg) sed[wid][rank] = eid;
  __syncthreads();
  float acc[NBAS][8] = {};
  for (int j = 0; j < deg; ++j){
    int e = sed[wid][j];
    int s = ei[e];
    int t = etype[e];
    float w = we[e];
    float c0 = w * satt[t * 4 + 0], c1 = w * satt[t * 4 + 1];
    float c2 = w * satt[t * 4 + 2], c3 = w * satt[t * 4 + 3];
    s8v xv = *reinterpret_cast<const s8v*>(xsrc + (size_t)s * 512 + lane * 8);
    #pragma unroll
    for (int jj = 0; jj < 8; ++jj){
      float x = bf2f((unsigned short)xv[jj]);
      acc[0][jj] = fmaf(c0, x, acc[0][jj]);
      acc[1][jj] = fmaf(c1, x, acc[1][jj]);
      acc[2][jj] = fmaf(c2, x, acc[2][jj]);
      acc[3][jj] = fmaf(c3, x, acc[3][jj]);
    }
  }
  #pragma unroll
  for (int b = 0; b < NBAS; ++b){
    s8v o;
    #pragma unroll
    for (int jj = 0; jj < 8; ++jj) o[jj] = (short)f2bf(acc[b][jj]);
    *reinterpret_cast<s8v*>(Ap + ((size_t)(n >> 4) * KT_L + b * 16 + (lane >> 2)) * 512
                               + ((n & 15) + (lane & 3) * 16) * 8) = o;
  }
}

// ---------------- pooling + pred assembly + normalize + pack ----------------
__global__ __launch_bounds__(256) void k_pred(const float* __restrict__ h2,
    const float* __restrict__ emb, const int* __restrict__ uniq,
    const int* __restrict__ pent_idx, const int* __restrict__ ptime_idx,
    const int* __restrict__ ent_c, const int* __restrict__ time_c,
    const float* __restrict__ qlin, const float* __restrict__ pent,
    unsigned short* __restrict__ Ap_pred){
  int w = (int)((blockIdx.x * 256 + threadIdx.x) >> 6);
  int lane = threadIdx.x & 63;
  if (w >= BATCH) return;
  float ae[8] = {}, at[8] = {};
  for (int j = 0; j < PENT; ++j){
    int idx = pent_idx[w * PENT + j];
    if (idx < NN){
      const float* p = h2 + (size_t)idx * 512 + lane * 8;
      #pragma unroll
      for (int jj = 0; jj < 8; ++jj) ae[jj] += p[jj];
    }
  }
  for (int j = 0; j < PTIME; ++j){
    int ti = ptime_idx[w * PTIME + j];
    if (ti < TUNIQ){
      const float* p = emb + (size_t)(NUM_ENT + uniq[ti]) * 512 + lane * 8;
      #pragma unroll
      for (int jj = 0; jj < 8; ++jj) at[jj] += p[jj];
    }
  }
  float ce = 1.f / (float)ent_c[w], ct = 1.f / (float)time_c[w];
  float p = pent[w];
  float pr[8]; float ss = 0.f;
  #pragma unroll
  for (int jj = 0; jj < 8; ++jj){
    float v = (qlin[(size_t)w * 512 + lane * 8 + jj] + ae[jj] * ce * p + at[jj] * ct * (1.f - p)) * (1.f / 3.f);
    pr[jj] = v; ss += v * v;
  }
  ss += __shfl_xor(ss, 32); ss += __shfl_xor(ss, 16); ss += __shfl_xor(ss, 8);
  ss += __shfl_xor(ss, 4);  ss += __shfl_xor(ss, 2);  ss += __shfl_xor(ss, 1);
  float inv = 1.f / fmaxf(sqrtf(ss), 1e-8f);
  s8v o;
  #pragma unroll
  for (int jj = 0; jj < 8; ++jj) o[jj] = (short)f2bf(pr[jj] * inv);
  *reinterpret_cast<s8v*>(Ap_pred + ((size_t)((w >> 4) * KT_E + (lane >> 2)) << 9)
                                  + ((w & 15) + (lane & 3) * 16) * 8) = o;
}

// ---------------- launch ----------------
extern "C" void kernel_launch(void* const* d_in, const int* in_sizes, int n_in,
                              void* d_out, int out_size, void* d_ws, size_t ws_size,
                              hipStream_t stream){
  const float* emb    = (const float*)d_in[0];
  const float* basis1 = (const float*)d_in[1];
  const float* att1   = (const float*)d_in[2];
  const float* root1  = (const float*)d_in[3];
  const float* bias1  = (const float*)d_in[4];
  const float* basis2 = (const float*)d_in[5];
  const float* att2   = (const float*)d_in[6];
  const float* root2  = (const float*)d_in[7];
  const float* bias2  = (const float*)d_in[8];
  const float* W_lin  = (const float*)d_in[9];
  const float* b_lin  = (const float*)d_in[10];
  const float* W_attn = (const float*)d_in[11];
  const float* b_attn = (const float*)d_in[12];
  const float* W_prob = (const float*)d_in[13];
  const float* b_prob = (const float*)d_in[14];
  const float* ques   = (const float*)d_in[15];
  const int* x_idx    = (const int*)d_in[16];
  const int* eidx     = (const int*)d_in[17];
  const int* etype    = (const int*)d_in[18];
  const int* stime    = (const int*)d_in[19];
  const int* etime    = (const int*)d_in[20];
  const int* ebatch   = (const int*)d_in[21];
  const float* enorm  = (const float*)d_in[22];
  const int* uniq     = (const int*)d_in[23];
  const int* pent_i   = (const int*)d_in[24];
  const int* ptime_i  = (const int*)d_in[25];
  const int* ent_c    = (const int*)d_in[26];
  const int* time_c   = (const int*)d_in[27];
  float* out = (float*)d_out;

  char* w = (char*)d_ws;
  size_t off = 0;
  auto alloc = [&](size_t bytes)->char*{ char* p = w + off; off += (bytes + 255) & ~(size_t)255; return p; };
  unsigned short* Bp_emb = (unsigned short*)alloc((size_t)KT_E * VT16 * 1024);      // 112.9 MB
  float*          invn   = (float*)alloc((size_t)V_PAD * 4);
  unsigned short* Ap     = (unsigned short*)alloc((size_t)(M_PAD / 16) * KT_L * 1024); // 154 MB
  unsigned short* B1p    = (unsigned short*)alloc((size_t)KT_L * 32 * 1024);
  unsigned short* B2p    = (unsigned short*)alloc((size_t)KT_L * 32 * 1024);
  char* xh_base = alloc((size_t)NN * 512 * 2 * 2);   // x_rm + h1 (bf16), overlaid later by h2 (f32)
  unsigned short* x_rm = (unsigned short*)xh_base;
  unsigned short* h1   = (unsigned short*)(xh_base + (size_t)NN * 512 * 2);
  float*          h2   = (float*)xh_base;            // overlay: used only after x_rm/h1 are dead
  float* M2    = (float*)alloc((size_t)BATCH * NTIMES * 4);
  float* we    = (float*)alloc((size_t)NEDGE * 4);
  float* qlin  = (float*)alloc((size_t)BATCH * 512 * 4);
  float* qattn = (float*)alloc((size_t)BATCH * 512 * 4);
  float* pent  = (float*)alloc(1024);
  unsigned short* Apq    = (unsigned short*)alloc((size_t)8 * KT_E * 1024);
  unsigned short* Appred = (unsigned short*)alloc((size_t)8 * KT_E * 1024);
  int* cnt   = (int*)alloc((size_t)NN * 4);
  int* lists = (int*)alloc((size_t)NN * 64 * 4);
  (void)ws_size; (void)in_sizes; (void)n_in; (void)out_size;

  // 1. emb -> bf16 B-layout + row inv-norms
  k_conv_emb<<<VT16, 256, 0, stream>>>(emb, Bp_emb, invn);
  // 2. question projections
  k_small<<<BATCH, 256, 0, stream>>>(ques, W_lin, b_lin, W_attn, b_attn, W_prob, b_prob,
                                     qlin, qattn, pent);
  k_pack_qrows<<<32, 256, 0, stream>>>(qattn, Apq);
  // 3. B packs for both layers
  k_pack_B<<<(KT_L * 32 * 64 + 255) / 256, 256, 0, stream>>>(basis1, root1, B1p);
  k_pack_B<<<(KT_L * 32 * 64 + 255) / 256, 256, 0, stream>>>(basis2, root2, B2p);
  // 4. M2 = q_attn @ time_emb^T   (cols offset NUM_ENT -> col-tile 6250)
  k_gemm<0><<<dim3(1, 79), 256, 0, stream>>>(Apq, Bp_emb, KT_E, VT16, NUM_ENT / 16,
                                             nullptr, nullptr, M2, nullptr);
  // 5. per-edge gate weights
  k_edge_w<<<(NEDGE + 255) / 256, 256, 0, stream>>>(ebatch, stime, etime, enorm, M2, we);
  // 6. bucket edges by dst
  hipMemsetAsync(cnt, 0, (size_t)NN * 4, stream);
  k_count<<<(NEDGE + 255) / 256, 256, 0, stream>>>(eidx, cnt, lists);
  // 7. gather x rows
  k_gather_x<<<NN / 4, 256, 0, stream>>>(x_idx, Bp_emb, Ap, x_rm);
  // 8. layer 1
  k_edge_agg<<<NN / 4, 256, 0, stream>>>(x_rm, eidx, etype, we, att1, cnt, lists, Ap);
  k_gemm<1><<<dim3(M_PAD / 128, 4), 256, 0, stream>>>(Ap, B1p, KT_L, 32, 0,
                                                      bias1, nullptr, nullptr, h1);
  // 9. layer 2
  k_pack_rows<<<NN / 4, 256, 0, stream>>>(h1, Ap);
  k_edge_agg<<<NN / 4, 256, 0, stream>>>(h1, eidx, etype, we, att2, cnt, lists, Ap);
  k_gemm<2><<<dim3(M_PAD / 128, 4), 256, 0, stream>>>(Ap, B2p, KT_L, 32, 0,
                                                      bias2, nullptr, h2, nullptr);
  // 10. pooling + pred
  k_pred<<<32, 256, 0, stream>>>(h2, emb, uniq, pent_i, ptime_i, ent_c, time_c,
                                 qlin, pent, Appred);
  // 11. score = 30 * pred_n @ emb_n^T
  k_gemm<3><<<dim3(1, V_PAD / 128), 256, 0, stream>>>(Appred, Bp_emb, KT_E, VT16, 0,
                                                      nullptr, invn, out, nullptr);
}